// Round 3
// baseline (181.073 us; speedup 1.0000x reference)
//
#include <hip/hip_runtime.h>
#include <hip/hip_bf16.h>

// Problem constants
#define B_   16
#define C_   256
#define T_   2048
#define PS   12
#define NNEG 15
#define OFFS 16
#define COPIES 16

// Derived
#define M_GEMM (B_ * T_)        // 32768 rows (b,t)
#define N_GEMM (C_ * PS)        // 3072 cols (j = i*256 + o)
#define K_GEMM C_               // 256
#define NPRED 6225408           // sum_i (2032-i)*256
#define NLAB  389088

using bf16 = __hip_bfloat16;
typedef __attribute__((ext_vector_type(4))) float f32x4;
typedef __attribute__((ext_vector_type(8))) short bf16x8;

#define WAITVM(n) asm volatile("s_waitcnt vmcnt(" #n ")" ::: "memory")
#define GLL(src, dst)                                                        \
    __builtin_amdgcn_global_load_lds(                                        \
        (const __attribute__((address_space(1))) void*)(src),                \
        (__attribute__((address_space(3))) void*)(dst), 16, 0, 0)

// ---------------------------------------------------------------- transpose z
// z[b][c][t] f32  ->  zT[b][t][c] bf16
__global__ __launch_bounds__(256) void transpose_z(const float* __restrict__ z,
                                                   bf16* __restrict__ zT) {
    __shared__ float tile[32][33];
    int t0 = blockIdx.x * 32, c0 = blockIdx.y * 32, b = blockIdx.z;
    int col = threadIdx.x & 31, r = threadIdx.x >> 5;
    for (int rr = 0; rr < 4; ++rr) {
        int row = r + rr * 8;
        tile[row][col] = z[(size_t)(b * C_ + c0 + row) * T_ + t0 + col];
    }
    __syncthreads();
    for (int rr = 0; rr < 4; ++rr) {
        int row = r + rr * 8;
        zT[(size_t)(b * T_ + t0 + row) * C_ + c0 + col] =
            __float2bfloat16(tile[col][row]);
    }
}

// ---------------------------------------------------------------- pack weight
// w[c][o][i] f32 -> wTb[j][c] bf16 with j = i*256 + o
__global__ __launch_bounds__(256) void pack_w(const float* __restrict__ w,
                                              bf16* __restrict__ wTb) {
    int gid = blockIdx.x * 256 + threadIdx.x;
    int j = gid >> 8, c = gid & 255;
    int o = j & 255, i = j >> 8;
    wTb[gid] = __float2bfloat16(w[(size_t)c * (C_ * PS) + o * PS + i]);
}

// ---------------------------------------------------------------- z_pred GEMM
// 256x256 tile, 8 waves (2Mx4N), BK=32, depth-4 counted-vmcnt LDS pipeline.
// zp_diag[b][s][i][o] = z_pred[b,o,s-16-i,i] + bias[o],  s = t+16+i < T
// LDS: 4 slots x 32KB. Slot: A [2 halves][128 rows][32 k] swz + B same @+16K.
// Swizzle: 16B granule g' = g ^ ((row>>1)&3), both sides (source-permuted
// global addr for global_load_lds; XOR applied again on ds_read).
#define EPAD 264   // epilogue row stride in bf16

__global__ __launch_bounds__(512, 2) void gemm_zpred(
    const bf16* __restrict__ zT, const bf16* __restrict__ wTb,
    const float* __restrict__ bias, bf16* __restrict__ zp) {
    __shared__ __align__(16) char smem[131072];
    bf16* lE = (bf16*)smem;

    // bijective XCD swizzle: grid = 1536 = 8 * 192
    int bid = (blockIdx.x & 7) * 192 + (blockIdx.x >> 3);
    int bm = bid / (N_GEMM / 256);   // 0..127
    int bn = bid % (N_GEMM / 256);   // 0..11  == prediction step i
    int row0 = bm * 256;
    int col0 = bn * 256;

    int tid = threadIdx.x;
    int wid = tid >> 6, lane = tid & 63;
    int ln15 = lane & 15, kg = lane >> 4;
    int wr = wid >> 2, wc = wid & 3;     // 2 x 4 wave grid; wave tile 128x64

    // ---- staging source pointers (per-lane, swizzle-permuted granule)
    int srow = wid * 16 + (lane >> 2);               // 0..127
    int gsw = ((lane & 3) ^ ((srow >> 1) & 3)) * 8;  // element offset in row
    const bf16* srcA0 = zT + (size_t)(row0 + srow) * 256 + gsw;
    const bf16* srcA1 = srcA0 + 128 * 256;
    const bf16* srcB0 = wTb + (size_t)(col0 + srow) * 256 + gsw;
    const bf16* srcB1 = srcB0 + 128 * 256;

    // ---- fragment LDS byte offsets within a slot (constant across iters)
    int offA[8], offB[4];
#pragma unroll
    for (int mi = 0; mi < 8; ++mi) {
        int rl = wr * 128 + mi * 16 + ln15;          // 0..255
        offA[mi] = (rl >> 7) * 8192 + (rl & 127) * 64 +
                   ((kg ^ ((rl >> 1) & 3)) * 16);
    }
#pragma unroll
    for (int ni = 0; ni < 4; ++ni) {
        int cl = wc * 64 + ni * 16 + ln15;           // 0..255
        offB[ni] = (cl >> 7) * 8192 + (cl & 127) * 64 +
                   ((kg ^ ((cl >> 1) & 3)) * 16);
    }

    f32x4 acc[8][4] = {};

#define STAGE(t, slot)                                                       \
    {                                                                        \
        const bf16* a0 = srcA0 + (t) * 32;                                   \
        const bf16* b0 = srcB0 + (t) * 32;                                   \
        char* d = smem + (slot) * 32768 + wid * 1024;                        \
        GLL(a0, d);                                                          \
        GLL(srcA1 + (t) * 32, d + 8192);                                     \
        GLL(b0, d + 16384);                                                  \
        GLL(srcB1 + (t) * 32, d + 24576);                                    \
    }

#define TILE_ITER(KT, VM)                                                    \
    {                                                                        \
        WAITVM(VM);                                                          \
        __builtin_amdgcn_s_barrier();                                        \
        char* sb = smem + ((KT) & 3) * 32768;                                \
        bf16x8 af[8], bfr[4];                                                \
        _Pragma("unroll") for (int mi = 0; mi < 8; ++mi)                     \
            af[mi] = *(const bf16x8*)(sb + offA[mi]);                        \
        _Pragma("unroll") for (int ni = 0; ni < 4; ++ni)                     \
            bfr[ni] = *(const bf16x8*)(sb + 16384 + offB[ni]);               \
        asm volatile("s_waitcnt lgkmcnt(0)" ::: "memory");                   \
        __builtin_amdgcn_sched_barrier(0);                                   \
        __builtin_amdgcn_s_barrier();                                        \
        if ((KT) + 4 < 8) STAGE((KT) + 4, (KT) & 3);                         \
        __builtin_amdgcn_s_setprio(1);                                       \
        _Pragma("unroll") for (int mi = 0; mi < 8; ++mi)                     \
            _Pragma("unroll") for (int ni = 0; ni < 4; ++ni)                 \
                acc[mi][ni] = __builtin_amdgcn_mfma_f32_16x16x32_bf16(       \
                    af[mi], bfr[ni], acc[mi][ni], 0, 0, 0);                  \
        __builtin_amdgcn_s_setprio(0);                                       \
    }

    // prologue: fill the 4-slot pipeline
    STAGE(0, 0);
    STAGE(1, 1);
    STAGE(2, 2);
    STAGE(3, 3);

    TILE_ITER(0, 12);
    TILE_ITER(1, 12);
    TILE_ITER(2, 12);
    TILE_ITER(3, 12);
    TILE_ITER(4, 12);
    TILE_ITER(5, 8);
    TILE_ITER(6, 4);
    TILE_ITER(7, 0);

    // ---------------- epilogue: two 128-row halves via LDS, coalesced stores
    float bv[4];
#pragma unroll
    for (int ni = 0; ni < 4; ++ni) bv[ni] = bias[wc * 64 + ni * 16 + ln15];

    for (int h = 0; h < 2; ++h) {
        __syncthreads();
        if (wr == h) {
#pragma unroll
            for (int mi = 0; mi < 8; ++mi)
#pragma unroll
                for (int ni = 0; ni < 4; ++ni) {
                    int cl = wc * 64 + ni * 16 + ln15;
#pragma unroll
                    for (int r = 0; r < 4; ++r) {
                        int row_e = mi * 16 + kg * 4 + r;
                        lE[row_e * EPAD + cl] =
                            __float2bfloat16(acc[mi][ni][r] + bv[ni]);
                    }
                }
        }
        __syncthreads();
#pragma unroll
        for (int e = 0; e < 8; ++e) {
            int row_e = e * 16 + (tid >> 5);
            int grow = row0 + h * 128 + row_e;
            int b = grow >> 11, t = grow & (T_ - 1);
            int s = t + OFFS + bn;
            if (s < T_) {
                bf16x8 v = *(const bf16x8*)&lE[row_e * EPAD + (tid & 31) * 8];
                *(bf16x8*)(zp + ((size_t)(b * T_ + s) * PS + bn) * 256 +
                           (tid & 31) * 8) = v;
            }
        }
    }
#undef STAGE
#undef TILE_ITER
}

// ---------------------------------------------------------------- predictions
// one wave per (b, s): D[n][i] = sum_c targets[n][c] * zp_diag[b][s][i][c]
__global__ __launch_bounds__(256) void predict_kernel(
    const bf16* __restrict__ zT, const bf16* __restrict__ zp,
    const int* __restrict__ neg, float* __restrict__ out) {
    int tid = threadIdx.x;
    int wid = tid >> 6, lane = tid & 63;
    int ln15 = lane & 15, kg = lane >> 4;
    int gw = blockIdx.x * 4 + wid;
    int b = gw / (T_ - OFFS);
    int s = OFFS + gw % (T_ - OFFS);

    int src;
    if (ln15 == 0) src = b * T_ + s;
    else           src = neg[b * (NNEG * T_) + (ln15 - 1) * T_ + s];
    const bf16* arow = zT + (size_t)src * 256 + kg * 8;
    const bf16* brow = zp + ((size_t)(b * T_ + s) * PS + ln15) * 256 + kg * 8;

    f32x4 acc = {0.f, 0.f, 0.f, 0.f};
#pragma unroll
    for (int kk = 0; kk < 8; ++kk) {
        bf16x8 a = *(const bf16x8*)(arow + kk * 32);
        bf16x8 bb = *(const bf16x8*)(brow + kk * 32);
        acc = __builtin_amdgcn_mfma_f32_16x16x32_bf16(a, bb, acc, 0, 0, 0);
    }

    int i = ln15;
    int imax = s - OFFS; if (imax > PS - 1) imax = PS - 1;
    if (i <= imax) {
        int t = s - OFFS - i;
        int base_i = 256 * ((T_ - OFFS) * i - (i * (i - 1)) / 2);
        float* o = out + base_i + (t * B_ + b) * COPIES + kg * 4;
        o[0] = acc[0]; o[1] = acc[1]; o[2] = acc[2]; o[3] = acc[3];
    }
}

// ---------------------------------------------------------------- launch
extern "C" void kernel_launch(void* const* d_in, const int* in_sizes, int n_in,
                              void* d_out, int out_size, void* d_ws, size_t ws_size,
                              hipStream_t stream) {
    const float* z    = (const float*)d_in[0];
    const float* w    = (const float*)d_in[1];
    const float* bias = (const float*)d_in[2];
    const int*   neg  = (const int*)d_in[3];
    float* out = (float*)d_out;

    char* ws = (char*)d_ws;
    const size_t ZP_BYTES = (size_t)B_ * T_ * PS * 256 * sizeof(bf16);
    bf16* zp  = (bf16*)ws;
    bf16* zT  = (bf16*)(ws + ZP_BYTES + 8192);
    bf16* wTb = (bf16*)(ws + ZP_BYTES + 8192 + (size_t)M_GEMM * 256 * sizeof(bf16));

    transpose_z<<<dim3(T_ / 32, C_ / 32, B_), 256, 0, stream>>>(z, zT);
    pack_w<<<(N_GEMM * 256) / 256, 256, 0, stream>>>(w, wTb);
    gemm_zpred<<<(M_GEMM / 256) * (N_GEMM / 256), 512, 0, stream>>>(zT, wTb, bias, zp);
    predict_kernel<<<(B_ * (T_ - OFFS)) / 4, 256, 0, stream>>>(zT, zp, neg, out);
    hipMemsetAsync(out + NPRED, 0, NLAB * sizeof(float), stream);
}

// Round 4
// 159.858 us; speedup vs baseline: 1.1327x; 1.1327x over previous
//
#include <hip/hip_runtime.h>
#include <hip/hip_bf16.h>

// Problem constants
#define B_   16
#define C_   256
#define T_   2048
#define PS   12
#define NNEG 15
#define OFFS 16
#define COPIES 16

// Derived
#define M_GEMM (B_ * T_)        // 32768 rows (b,t)
#define N_GEMM (C_ * PS)        // 3072 cols (j = i*256 + o)
#define K_GEMM C_               // 256
#define NPRED 6225408           // sum_i (2032-i)*256
#define NLAB  389088

using bf16 = __hip_bfloat16;
typedef __attribute__((ext_vector_type(4))) float f32x4;
typedef __attribute__((ext_vector_type(8))) short bf16x8;

#define WAITVM(n) asm volatile("s_waitcnt vmcnt(" #n ")" ::: "memory")
#define GLL(src, dst)                                                        \
    __builtin_amdgcn_global_load_lds(                                        \
        (const __attribute__((address_space(1))) void*)(src),                \
        (__attribute__((address_space(3))) void*)(dst), 16, 0, 0)

// ---------------------------------------------------------------- transpose z
// z[b][c][t] f32  ->  zT[b][t][c] bf16
__global__ __launch_bounds__(256) void transpose_z(const float* __restrict__ z,
                                                   bf16* __restrict__ zT) {
    __shared__ float tile[32][33];
    int t0 = blockIdx.x * 32, c0 = blockIdx.y * 32, b = blockIdx.z;
    int col = threadIdx.x & 31, r = threadIdx.x >> 5;
    for (int rr = 0; rr < 4; ++rr) {
        int row = r + rr * 8;
        tile[row][col] = z[(size_t)(b * C_ + c0 + row) * T_ + t0 + col];
    }
    __syncthreads();
    for (int rr = 0; rr < 4; ++rr) {
        int row = r + rr * 8;
        zT[(size_t)(b * T_ + t0 + row) * C_ + c0 + col] =
            __float2bfloat16(tile[col][row]);
    }
}

// ---------------------------------------------------------------- pack weight
// w[c][o][i] f32 -> wTb[j][c] bf16 with j = i*256 + o
__global__ __launch_bounds__(256) void pack_w(const float* __restrict__ w,
                                              bf16* __restrict__ wTb) {
    int gid = blockIdx.x * 256 + threadIdx.x;
    int j = gid >> 8, c = gid & 255;
    int o = j & 255, i = j >> 8;
    wTb[gid] = __float2bfloat16(w[(size_t)c * (C_ * PS) + o * PS + i]);
}

// ---------------------------------------------------------------- z_pred GEMM
// 128x128 tile, 4 waves (2x2), BK=32, depth-3 counted-vmcnt LDS pipeline.
// LDS: 3 slots x 16KB (A [128][32] swz @0, B same @8192). 48KB -> 3 blocks/CU.
// Swizzle: 16B granule g' = g ^ ((row>>1)&3), applied on BOTH sides
// (pre-swizzled global source for global_load_lds; XOR again on ds_read).
// zp_diag[b][s][i][o] = z_pred[b,o,s-16-i,i] + bias[o],  s = t+16+i < T
#define EPAD 136

__global__ __launch_bounds__(256) void gemm_zpred(const bf16* __restrict__ zT,
                                                  const bf16* __restrict__ wTb,
                                                  const float* __restrict__ bias,
                                                  bf16* __restrict__ zp) {
    __shared__ __align__(16) char smem[49152];
    bf16* lE = (bf16*)smem;

    // bijective XCD swizzle: grid = 6144 = 8 * 768
    int bid = (blockIdx.x & 7) * 768 + (blockIdx.x >> 3);
    int bn = bid % (N_GEMM / 128);   // 24
    int bm = bid / (N_GEMM / 128);   // 256
    int tid = threadIdx.x;
    int wid = tid >> 6, lane = tid & 63;
    int ln15 = lane & 15, kg = lane >> 4;
    int wm = (wid & 1) * 64, wn = (wid >> 1) * 64;
    int row0 = bm * 128, col0 = bn * 128;
    int i_step = col0 >> 8;
    int o0 = col0 & 255;

    // staging source: GLL j covers rows j*64 + wid*16 + (lane>>2), granule
    // (lane&3); pre-swizzled source granule = (lane&3) ^ ((lane>>3)&3)
    // (since (row>>1)&3 == (lane>>3)&3 for these rows).
    int gsw = ((lane & 3) ^ ((lane >> 3) & 3)) * 8;
    int srow = wid * 16 + (lane >> 2);
    const bf16* srcA = zT + (size_t)(row0 + srow) * 256 + gsw;
    const bf16* srcB = wTb + (size_t)(col0 + srow) * 256 + gsw;

    // fragment LDS byte offsets within a slot
    int offA[4], offB[4];
#pragma unroll
    for (int mi = 0; mi < 4; ++mi) {
        int r = wm + mi * 16 + ln15;
        offA[mi] = r * 64 + ((kg ^ ((r >> 1) & 3)) * 16);
    }
#pragma unroll
    for (int ni = 0; ni < 4; ++ni) {
        int c = wn + ni * 16 + ln15;
        offB[ni] = 8192 + c * 64 + ((kg ^ ((c >> 1) & 3)) * 16);
    }

    f32x4 acc[4][4] = {};

#define STAGE(t, slot_base)                                                  \
    {                                                                        \
        char* d = smem + (slot_base) + wid * 1024;                           \
        const bf16* sa = srcA + (t) * 32;                                    \
        const bf16* sb2 = srcB + (t) * 32;                                   \
        GLL(sa, d);                                                          \
        GLL(sa + 64 * 256, d + 4096);                                        \
        GLL(sb2, d + 8192);                                                  \
        GLL(sb2 + 64 * 256, d + 12288);                                      \
    }

#define TILE_BODY(slot_base, VMN)                                            \
    {                                                                        \
        WAITVM(VMN);                                                         \
        __builtin_amdgcn_s_barrier();                                        \
        const char* sb = smem + (slot_base);                                 \
        bf16x8 af[4], bfr[4];                                                \
        _Pragma("unroll") for (int mi = 0; mi < 4; ++mi)                     \
            af[mi] = *(const bf16x8*)(sb + offA[mi]);                        \
        _Pragma("unroll") for (int ni = 0; ni < 4; ++ni)                     \
            bfr[ni] = *(const bf16x8*)(sb + offB[ni]);                       \
        asm volatile("s_waitcnt lgkmcnt(0)" ::: "memory");                   \
        __builtin_amdgcn_sched_barrier(0);                                   \
        __builtin_amdgcn_s_barrier();                                        \
        __builtin_amdgcn_s_setprio(1);                                       \
        _Pragma("unroll") for (int mi = 0; mi < 4; ++mi)                     \
            _Pragma("unroll") for (int ni = 0; ni < 4; ++ni)                 \
                acc[mi][ni] = __builtin_amdgcn_mfma_f32_16x16x32_bf16(       \
                    af[mi], bfr[ni], acc[mi][ni], 0, 0, 0);                  \
        __builtin_amdgcn_s_setprio(0);                                       \
    }

    // prologue: fill 2 slots; each tile stages t+2 into the just-freed slot
    STAGE(0, 0);
    STAGE(1, 16384);
    STAGE(2, 32768);  TILE_BODY(0, 8);       // tile 0
    STAGE(3, 0);      TILE_BODY(16384, 8);   // tile 1
    STAGE(4, 16384);  TILE_BODY(32768, 8);   // tile 2
    STAGE(5, 32768);  TILE_BODY(0, 8);       // tile 3
    STAGE(6, 0);      TILE_BODY(16384, 8);   // tile 4
    STAGE(7, 16384);  TILE_BODY(32768, 8);   // tile 5
                      TILE_BODY(0, 4);       // tile 6
                      TILE_BODY(16384, 0);   // tile 7

    // ---------------- epilogue: acc -> LDS (bf16, +bias) -> coalesced stores
    __syncthreads();

    float bv[4];
#pragma unroll
    for (int ni = 0; ni < 4; ++ni) bv[ni] = bias[o0 + wn + ni * 16 + ln15];

#pragma unroll
    for (int mi = 0; mi < 4; ++mi)
#pragma unroll
        for (int ni = 0; ni < 4; ++ni) {
            int col_e = wn + ni * 16 + ln15;
#pragma unroll
            for (int r = 0; r < 4; ++r) {
                int row_e = wm + mi * 16 + kg * 4 + r;
                lE[row_e * EPAD + col_e] = __float2bfloat16(acc[mi][ni][r] + bv[ni]);
            }
        }

    __syncthreads();

#pragma unroll
    for (int e = 0; e < 8; ++e) {
        int row_e = e * 16 + (tid >> 4);
        int grow = row0 + row_e;
        int b = grow >> 11, t = grow & (T_ - 1);
        int s = t + OFFS + i_step;
        if (s < T_) {
            bf16x8 v = *(const bf16x8*)&lE[row_e * EPAD + (tid & 15) * 8];
            *(bf16x8*)(zp + ((size_t)(b * T_ + s) * PS + i_step) * 256 + o0 +
                       (tid & 15) * 8) = v;
        }
    }
#undef STAGE
#undef TILE_BODY
}

// ---------------------------------------------------------------- predictions
// one wave per TWO consecutive (b,s): doubles loads-in-flight + 2 MFMA chains.
// D[n][i] = sum_c targets[n][c] * zp_diag[b][s][i][c]
__global__ __launch_bounds__(256) void predict_kernel(
    const bf16* __restrict__ zT, const bf16* __restrict__ zp,
    const int* __restrict__ neg, float* __restrict__ out) {
    int tid = threadIdx.x;
    int wid = tid >> 6, lane = tid & 63;
    int ln15 = lane & 15, kg = lane >> 4;
    int gw = (blockIdx.x * 4 + wid) * 2;   // first of the pair; 2032 even ->
    int b = gw / (T_ - OFFS);              // pair never straddles b
    int s = OFFS + gw % (T_ - OFFS);

    int src0, src1;
    if (ln15 == 0) {
        src0 = b * T_ + s;
        src1 = src0 + 1;
    } else {
        const int* np = neg + b * (NNEG * T_) + (ln15 - 1) * T_ + s;
        src0 = np[0];
        src1 = np[1];
    }
    const bf16* a0 = zT + (size_t)src0 * 256 + kg * 8;
    const bf16* a1 = zT + (size_t)src1 * 256 + kg * 8;
    const bf16* b0 = zp + ((size_t)(b * T_ + s) * PS + ln15) * 256 + kg * 8;
    const bf16* b1 = b0 + PS * 256;

    f32x4 acc0 = {0.f, 0.f, 0.f, 0.f};
    f32x4 acc1 = {0.f, 0.f, 0.f, 0.f};
#pragma unroll
    for (int kk = 0; kk < 8; ++kk) {
        bf16x8 av0 = *(const bf16x8*)(a0 + kk * 32);
        bf16x8 bv0 = *(const bf16x8*)(b0 + kk * 32);
        bf16x8 av1 = *(const bf16x8*)(a1 + kk * 32);
        bf16x8 bv1 = *(const bf16x8*)(b1 + kk * 32);
        acc0 = __builtin_amdgcn_mfma_f32_16x16x32_bf16(av0, bv0, acc0, 0, 0, 0);
        acc1 = __builtin_amdgcn_mfma_f32_16x16x32_bf16(av1, bv1, acc1, 0, 0, 0);
    }

    // D col = ln15 = step i ; D rows = kg*4 + r = target copy n
    int i = ln15;
    if (i < PS) {
#pragma unroll 2
        for (int p = 0; p < 2; ++p) {
            int sp = s + p;
            int imax = sp - OFFS;
            if (i <= imax) {
                int t = sp - OFFS - i;
                int base_i = 256 * ((T_ - OFFS) * i - (i * (i - 1)) / 2);
                float* o = out + base_i + (t * B_ + b) * COPIES + kg * 4;
                f32x4 a = p ? acc1 : acc0;
                o[0] = a[0]; o[1] = a[1]; o[2] = a[2]; o[3] = a[3];
            }
        }
    }
}

// ---------------------------------------------------------------- launch
extern "C" void kernel_launch(void* const* d_in, const int* in_sizes, int n_in,
                              void* d_out, int out_size, void* d_ws, size_t ws_size,
                              hipStream_t stream) {
    const float* z    = (const float*)d_in[0];
    const float* w    = (const float*)d_in[1];
    const float* bias = (const float*)d_in[2];
    const int*   neg  = (const int*)d_in[3];
    float* out = (float*)d_out;

    char* ws = (char*)d_ws;
    const size_t ZP_BYTES = (size_t)B_ * T_ * PS * 256 * sizeof(bf16);
    bf16* zp  = (bf16*)ws;                         // +8KB pad for tail overread
    bf16* zT  = (bf16*)(ws + ZP_BYTES + 8192);
    bf16* wTb = (bf16*)(ws + ZP_BYTES + 8192 + (size_t)M_GEMM * 256 * sizeof(bf16));

    transpose_z<<<dim3(T_ / 32, C_ / 32, B_), 256, 0, stream>>>(z, zT);
    pack_w<<<(N_GEMM * 256) / 256, 256, 0, stream>>>(w, wTb);
    gemm_zpred<<<(M_GEMM / 128) * (N_GEMM / 128), 256, 0, stream>>>(zT, wTb, bias, zp);
    predict_kernel<<<(B_ * (T_ - OFFS)) / 8, 256, 0, stream>>>(zT, zp, neg, out);
    hipMemsetAsync(out + NPRED, 0, NLAB * sizeof(float), stream);
}

// Round 5
// 152.032 us; speedup vs baseline: 1.1910x; 1.0515x over previous
//
#include <hip/hip_runtime.h>
#include <hip/hip_bf16.h>

// Problem constants
#define B_   16
#define C_   256
#define T_   2048
#define PS   12
#define NNEG 15
#define OFFS 16
#define COPIES 16

// Derived
#define M_GEMM (B_ * T_)        // 32768 rows (b,t)
#define N_GEMM (C_ * PS)        // 3072 cols (j = i*256 + o)
#define K_GEMM C_               // 256
#define NPRED 6225408           // sum_i (2032-i)*256
#define NLAB  389088

using bf16 = __hip_bfloat16;
typedef __attribute__((ext_vector_type(4))) float f32x4;
typedef __attribute__((ext_vector_type(8))) short bf16x8;

#define WAITVM(n) asm volatile("s_waitcnt vmcnt(" #n ")" ::: "memory")
#define GLL(src, dst)                                                        \
    __builtin_amdgcn_global_load_lds(                                        \
        (const __attribute__((address_space(1))) void*)(src),                \
        (__attribute__((address_space(3))) void*)(dst), 16, 0, 0)

// ---------------------------------------------------------------- transpose z
// z[b][c][t] f32  ->  zT[b][t][c] bf16
__global__ __launch_bounds__(256) void transpose_z(const float* __restrict__ z,
                                                   bf16* __restrict__ zT) {
    __shared__ float tile[32][33];
    int t0 = blockIdx.x * 32, c0 = blockIdx.y * 32, b = blockIdx.z;
    int col = threadIdx.x & 31, r = threadIdx.x >> 5;
    for (int rr = 0; rr < 4; ++rr) {
        int row = r + rr * 8;
        tile[row][col] = z[(size_t)(b * C_ + c0 + row) * T_ + t0 + col];
    }
    __syncthreads();
    for (int rr = 0; rr < 4; ++rr) {
        int row = r + rr * 8;
        zT[(size_t)(b * T_ + t0 + row) * C_ + c0 + col] =
            __float2bfloat16(tile[col][row]);
    }
}

// ---------------------------------------------------------------- pack weight
// w[c][o][i] f32 -> wTb[j][c] bf16 with j = i*256 + o
__global__ __launch_bounds__(256) void pack_w(const float* __restrict__ w,
                                              bf16* __restrict__ wTb) {
    int gid = blockIdx.x * 256 + threadIdx.x;
    int j = gid >> 8, c = gid & 255;
    int o = j & 255, i = j >> 8;
    wTb[gid] = __float2bfloat16(w[(size_t)c * (C_ * PS) + o * PS + i]);
}

// ---------------------------------------------------------------- z_pred GEMM
// 128x128 tile, 4 waves (2x2), BK=32, depth-3 counted-vmcnt LDS pipeline.
// (unchanged from round 4)
#define EPAD 136

__global__ __launch_bounds__(256) void gemm_zpred(const bf16* __restrict__ zT,
                                                  const bf16* __restrict__ wTb,
                                                  const float* __restrict__ bias,
                                                  bf16* __restrict__ zp) {
    __shared__ __align__(16) char smem[49152];
    bf16* lE = (bf16*)smem;

    int bid = (blockIdx.x & 7) * 768 + (blockIdx.x >> 3);
    int bn = bid % (N_GEMM / 128);
    int bm = bid / (N_GEMM / 128);
    int tid = threadIdx.x;
    int wid = tid >> 6, lane = tid & 63;
    int ln15 = lane & 15, kg = lane >> 4;
    int wm = (wid & 1) * 64, wn = (wid >> 1) * 64;
    int row0 = bm * 128, col0 = bn * 128;
    int i_step = col0 >> 8;
    int o0 = col0 & 255;

    int gsw = ((lane & 3) ^ ((lane >> 3) & 3)) * 8;
    int srow = wid * 16 + (lane >> 2);
    const bf16* srcA = zT + (size_t)(row0 + srow) * 256 + gsw;
    const bf16* srcB = wTb + (size_t)(col0 + srow) * 256 + gsw;

    int offA[4], offB[4];
#pragma unroll
    for (int mi = 0; mi < 4; ++mi) {
        int r = wm + mi * 16 + ln15;
        offA[mi] = r * 64 + ((kg ^ ((r >> 1) & 3)) * 16);
    }
#pragma unroll
    for (int ni = 0; ni < 4; ++ni) {
        int c = wn + ni * 16 + ln15;
        offB[ni] = 8192 + c * 64 + ((kg ^ ((c >> 1) & 3)) * 16);
    }

    f32x4 acc[4][4] = {};

#define STAGE(t, slot_base)                                                  \
    {                                                                        \
        char* d = smem + (slot_base) + wid * 1024;                           \
        const bf16* sa = srcA + (t) * 32;                                    \
        const bf16* sb2 = srcB + (t) * 32;                                   \
        GLL(sa, d);                                                          \
        GLL(sa + 64 * 256, d + 4096);                                        \
        GLL(sb2, d + 8192);                                                  \
        GLL(sb2 + 64 * 256, d + 12288);                                      \
    }

#define TILE_BODY(slot_base, VMN)                                            \
    {                                                                        \
        WAITVM(VMN);                                                         \
        __builtin_amdgcn_s_barrier();                                        \
        const char* sb = smem + (slot_base);                                 \
        bf16x8 af[4], bfr[4];                                                \
        _Pragma("unroll") for (int mi = 0; mi < 4; ++mi)                     \
            af[mi] = *(const bf16x8*)(sb + offA[mi]);                        \
        _Pragma("unroll") for (int ni = 0; ni < 4; ++ni)                     \
            bfr[ni] = *(const bf16x8*)(sb + offB[ni]);                       \
        asm volatile("s_waitcnt lgkmcnt(0)" ::: "memory");                   \
        __builtin_amdgcn_sched_barrier(0);                                   \
        __builtin_amdgcn_s_barrier();                                        \
        __builtin_amdgcn_s_setprio(1);                                       \
        _Pragma("unroll") for (int mi = 0; mi < 4; ++mi)                     \
            _Pragma("unroll") for (int ni = 0; ni < 4; ++ni)                 \
                acc[mi][ni] = __builtin_amdgcn_mfma_f32_16x16x32_bf16(       \
                    af[mi], bfr[ni], acc[mi][ni], 0, 0, 0);                  \
        __builtin_amdgcn_s_setprio(0);                                       \
    }

    STAGE(0, 0);
    STAGE(1, 16384);
    STAGE(2, 32768);  TILE_BODY(0, 8);
    STAGE(3, 0);      TILE_BODY(16384, 8);
    STAGE(4, 16384);  TILE_BODY(32768, 8);
    STAGE(5, 32768);  TILE_BODY(0, 8);
    STAGE(6, 0);      TILE_BODY(16384, 8);
    STAGE(7, 16384);  TILE_BODY(32768, 8);
                      TILE_BODY(0, 4);
                      TILE_BODY(16384, 0);

    __syncthreads();

    float bv[4];
#pragma unroll
    for (int ni = 0; ni < 4; ++ni) bv[ni] = bias[o0 + wn + ni * 16 + ln15];

#pragma unroll
    for (int mi = 0; mi < 4; ++mi)
#pragma unroll
        for (int ni = 0; ni < 4; ++ni) {
            int col_e = wn + ni * 16 + ln15;
#pragma unroll
            for (int r = 0; r < 4; ++r) {
                int row_e = wm + mi * 16 + kg * 4 + r;
                lE[row_e * EPAD + col_e] = __float2bfloat16(acc[mi][ni][r] + bv[ni]);
            }
        }

    __syncthreads();

#pragma unroll
    for (int e = 0; e < 8; ++e) {
        int row_e = e * 16 + (tid >> 4);
        int grow = row0 + row_e;
        int b = grow >> 11, t = grow & (T_ - 1);
        int s = t + OFFS + i_step;
        if (s < T_) {
            bf16x8 v = *(const bf16x8*)&lE[row_e * EPAD + (tid & 15) * 8];
            *(bf16x8*)(zp + ((size_t)(b * T_ + s) * PS + i_step) * 256 + o0 +
                       (tid & 15) * 8) = v;
        }
    }
#undef STAGE
#undef TILE_BODY
}

// ---------------------------------------------------------------- predictions
// One wave per (b,s) per iteration; 8 iterations; per-wave double-buffered
// LDS slots (16KB: A-targets 16x512B @0, zp 12x512B @8192), staged via
// global_load_lds (14 x 1KB per slot) with counted vmcnt(14) -> deep
// memory-level parallelism without VGPR cost. XOR swizzle granule^=(row&7)
// on both GLL-source and ds_read (2-way max conflicts).
__global__ __launch_bounds__(256) void predict_kernel(
    const bf16* __restrict__ zT, const bf16* __restrict__ zp,
    const int* __restrict__ neg, float* __restrict__ out) {
    __shared__ __align__(16) char psm[131072];
    int tid = threadIdx.x;
    int wid = tid >> 6, lane = tid & 63;
    int ln15 = lane & 15, kg = lane >> 4;
    char* my = psm + wid * 32768;           // wave-private: 2 slots x 16KB
    int base_gi = (blockIdx.x * 4 + wid) * 8;

    const char* zTb = (const char*)zT;
    const char* zpb = (const char*)zp;

    auto stage = [&](int it, int slot) {
        int gi = base_gi + it;
        int b = gi / (T_ - OFFS);
        int s = OFFS + gi % (T_ - OFFS);
        int srcrow = 0;
        if (lane < 16) {
            if (lane == 0) srcrow = b * T_ + s;
            else srcrow = neg[b * (NNEG * T_) + (lane - 1) * T_ + s];
        }
        char* dst = my + slot * 16384;
        int half = lane >> 5;               // 0/1: which row within the GLL
        int g31 = lane & 31;                // source granule position
#pragma unroll
        for (int j = 0; j < 8; ++j) {
            int r0 = __shfl(srcrow, 2 * j);
            int r1 = __shfl(srcrow, 2 * j + 1);
            int row = half ? r1 : r0;       // global zT row
            int n = 2 * j + half;           // local target row 0..15
            const char* src = zTb + (size_t)row * 512 + ((g31 ^ (n & 7)) << 4);
            GLL(src, dst + j * 1024);
        }
        size_t zoff = (size_t)(b * T_ + s) * (PS * 512);
#pragma unroll
        for (int j = 0; j < 6; ++j) {
            int i0 = 2 * j + half;          // zp row (step i) 0..11
            const char* src = zpb + zoff + i0 * 512 + ((g31 ^ (i0 & 7)) << 4);
            GLL(src, dst + 8192 + j * 1024);
        }
    };

    auto compute = [&](int it, int slot) {
        const char* sb = my + slot * 16384;
        int ii = ln15 < 12 ? ln15 : 0;      // dup col 0 for pad lanes (bcast)
        bf16x8 af[8], bfr[8];
#pragma unroll
        for (int kk = 0; kk < 8; ++kk) {
            int g = kk * 4 + kg;
            af[kk] = *(const bf16x8*)(sb + ln15 * 512 + ((g ^ (ln15 & 7)) << 4));
            bfr[kk] = *(const bf16x8*)(sb + 8192 + ii * 512 + ((g ^ (ii & 7)) << 4));
        }
        // frags in regs before this slot is overwritten by stage(it+2)
        asm volatile("s_waitcnt lgkmcnt(0)" ::: "memory");
        __builtin_amdgcn_sched_barrier(0);
        if (it + 2 < 8) stage(it + 2, slot);

        f32x4 acc = {0.f, 0.f, 0.f, 0.f};
#pragma unroll
        for (int kk = 0; kk < 8; ++kk)
            acc = __builtin_amdgcn_mfma_f32_16x16x32_bf16(af[kk], bfr[kk], acc,
                                                          0, 0, 0);

        int gi = base_gi + it;
        int b = gi / (T_ - OFFS);
        int s = OFFS + gi % (T_ - OFFS);
        int i = ln15;
        int imax = s - OFFS; if (imax > PS - 1) imax = PS - 1;
        if (i <= imax) {
            int t = s - OFFS - i;
            int base_i = 256 * ((T_ - OFFS) * i - (i * (i - 1)) / 2);
            float* o = out + base_i + (t * B_ + b) * COPIES + kg * 4;
            o[0] = acc[0]; o[1] = acc[1]; o[2] = acc[2]; o[3] = acc[3];
        }
    };

    stage(0, 0);
    stage(1, 1);
#pragma unroll
    for (int it = 0; it < 8; ++it) {
        if (it < 7) { WAITVM(14); }         // slot it landed; it+1 in flight
        else        { WAITVM(0);  }         // drain
        compute(it, it & 1);
    }
}

// ---------------------------------------------------------------- launch
extern "C" void kernel_launch(void* const* d_in, const int* in_sizes, int n_in,
                              void* d_out, int out_size, void* d_ws, size_t ws_size,
                              hipStream_t stream) {
    const float* z    = (const float*)d_in[0];
    const float* w    = (const float*)d_in[1];
    const float* bias = (const float*)d_in[2];
    const int*   neg  = (const int*)d_in[3];
    float* out = (float*)d_out;

    char* ws = (char*)d_ws;
    const size_t ZP_BYTES = (size_t)B_ * T_ * PS * 256 * sizeof(bf16);
    bf16* zp  = (bf16*)ws;
    bf16* zT  = (bf16*)(ws + ZP_BYTES + 8192);
    bf16* wTb = (bf16*)(ws + ZP_BYTES + 8192 + (size_t)M_GEMM * 256 * sizeof(bf16));

    transpose_z<<<dim3(T_ / 32, C_ / 32, B_), 256, 0, stream>>>(z, zT);
    pack_w<<<(N_GEMM * 256) / 256, 256, 0, stream>>>(w, wTb);
    gemm_zpred<<<(M_GEMM / 128) * (N_GEMM / 128), 256, 0, stream>>>(zT, wTb, bias, zp);
    // 1016 blocks x 4 waves x 8 iters = 32512 (b,s) pairs
    predict_kernel<<<(B_ * (T_ - OFFS)) / 32, 256, 0, stream>>>(zT, zp, neg, out);
    hipMemsetAsync(out + NPRED, 0, NLAB * sizeof(float), stream);
}